// Round 3
// baseline (377.879 us; speedup 1.0000x reference)
//
#include <hip/hip_runtime.h>

typedef __bf16 bf16_t;
typedef __bf16 bf16x8 __attribute__((ext_vector_type(8)));
typedef __bf16 bf16x4 __attribute__((ext_vector_type(4)));
typedef float  f32x4  __attribute__((ext_vector_type(4)));

// ---------------------------------------------------------------------------
// Workspace layout (floats unless noted):
//   A  : [4096][256] f32   (xf @ W1[0:26])                       4 MB
//   C  : [4096][256] f32   (xf @ W1[26:52] + qst @ W1[52:180] + b1)  4 MB
//   Wt : 3 x [256][256] bf16, g2/g3/g4 weights transposed [out][in]  384 KB
//   xg : [64][256] f32     (pair-summed g output)                64 KB
// ---------------------------------------------------------------------------

// swizzled LDS column index: 16B-block XOR on row low bits -> conflict-free
// ds_read_b128 A-fragment reads with zero padding (stays at exactly 32 KB).
__device__ __forceinline__ int swz(int row, int col) {
  return (((col >> 3) ^ (row & 7)) << 3) | (col & 7);
}

// ---------------- prep: A, C, weight transpose+cast, zero xg ----------------
__global__ __launch_bounds__(256) void rn_prep_kernel(
    const float* __restrict__ x, const float* __restrict__ qst,
    const float* __restrict__ g1w, const float* __restrict__ g1b,
    const float* __restrict__ g2w, const float* __restrict__ g3w,
    const float* __restrict__ g4w,
    float* __restrict__ A, float* __restrict__ C,
    bf16_t* __restrict__ Wt, float* __restrict__ xg)
{
  int blk = blockIdx.x;
  int n   = threadIdx.x;  // 0..255
  if (blk < 256) {
    // block = (b, jg): rows jg*16 .. jg*16+15 of batch b; thread = output col n
    int b  = blk >> 2;
    int jg = (blk & 3) * 16;
    // qst part (independent of row): accQ = b1[n] + sum_q qst[b,q]*W1[52+q, n]
    float accQ = g1b[n];
    const float* qb = qst + b * 128;
    #pragma unroll 8
    for (int qi = 0; qi < 128; ++qi)
      accQ += qb[qi] * g1w[(52 + qi) * 256 + n];

    float w24 = g1w[24 * 256 + n], w25 = g1w[25 * 256 + n];
    float w50 = g1w[50 * 256 + n], w51 = g1w[51 * 256 + n];
    float accA[16], accC[16];
    #pragma unroll
    for (int t = 0; t < 16; ++t) {
      int j = jg + t;
      // faithful to (a/d - d/2)/(d/2.0) float arithmetic, d=8 (exact pow2 ops)
      float cx = ((float)j * 0.125f - 4.0f) * 0.25f;
      float cy = ((float)(j & 7) - 4.0f) * 0.25f;
      accA[t] = cx * w24 + cy * w25;
      accC[t] = accQ + cx * w50 + cy * w51;
    }
    for (int c = 0; c < 24; ++c) {
      float wa = g1w[c * 256 + n];
      float wc = g1w[(26 + c) * 256 + n];
      const float* xc = x + (b * 24 + c) * 64 + jg;
      #pragma unroll
      for (int t = 0; t < 16; ++t) {
        float xv = xc[t];   // uniform per thread -> scalar load
        accA[t] += xv * wa;
        accC[t] += xv * wc;
      }
    }
    #pragma unroll
    for (int t = 0; t < 16; ++t) {
      A[(b * 64 + jg + t) * 256 + n] = accA[t];
      C[(b * 64 + jg + t) * 256 + n] = accC[t];
    }
  } else if (blk < 256 + 768) {
    // transpose g2/g3/g4 [in][out] -> bf16 [out][in]
    int idx = (blk - 256) * 256 + n;       // 0..196607
    int mat = idx >> 16;
    int e   = idx & 65535;
    int k   = e & 255;        // input dim (fastest -> coalesced writes)
    int no  = e >> 8;         // output dim
    const float* W = (mat == 0) ? g2w : (mat == 1 ? g3w : g4w);
    Wt[mat * 65536 + no * 256 + k] = (bf16_t)W[k * 256 + no];
  } else {
    int idx = (blk - (256 + 768)) * 256 + n;  // 64 blocks -> 16384
    xg[idx] = 0.f;
  }
}

// ---------------- main fused g-MLP (layers 2..4) + pair sum ----------------
// one block per (b, i): M = 64 rows (j), N = K = 256.
// wave w owns output columns [w*64, w*64+64).
// SINGLE 32 KB h buffer: all LDS reads of a layer finish before the epilogue
// writes start (extra __syncthreads between phases).
// NOTE: no min-waves clause — forcing 4 waves/EU clamped VGPRs to 64 and
// caused 168 MB of scratch spill traffic (R2). Natural allocation ~120 VGPR
// already fits 4 waves/EU (480 <= 512).
__global__ __launch_bounds__(256) void rn_main_kernel(
    const float* __restrict__ A, const float* __restrict__ C,
    const bf16_t* __restrict__ Wt,
    const float* __restrict__ g2b, const float* __restrict__ g3b,
    const float* __restrict__ g4b,
    float* __restrict__ xg)
{
  __shared__ bf16_t hbuf[64][256];   // exactly 32 KB, XOR-swizzled cols

  int tid  = threadIdx.x;
  int bx   = blockIdx.x;
  int b    = bx >> 6;
  int lane = tid & 63;
  int wave = tid >> 6;
  int n0   = wave * 64;

  // ---- build h1 = relu(A[b,j,:] + C[b,i,:]) into hbuf ----
  {
    const float* Crow = C + (size_t)bx * 256;        // row (b*64 + i)
    const float* Ab   = A + (size_t)b * 64 * 256;
    #pragma unroll
    for (int it = 0; it < 16; ++it) {
      int g = it * 256 + tid;
      int j = g >> 6;
      int n = (g & 63) * 4;
      const float4 a4 = *(const float4*)(Ab + j * 256 + n);
      const float4 c4 = *(const float4*)(Crow + n);
      bf16x4 v;
      v[0] = (bf16_t)fmaxf(a4.x + c4.x, 0.f);
      v[1] = (bf16_t)fmaxf(a4.y + c4.y, 0.f);
      v[2] = (bf16_t)fmaxf(a4.z + c4.z, 0.f);
      v[3] = (bf16_t)fmaxf(a4.w + c4.w, 0.f);
      *(bf16x4*)&hbuf[j][swz(j, n)] = v;
    }
  }

  const float* biases[3] = {g2b, g3b, g4b};
  int r = lane & 15;     // MFMA: A-row / B-col / D-col within 16x16 tile
  int q = lane >> 4;     // quad: k-chunk selector / D-row group

  for (int L = 0; L < 3; ++L) {
    __syncthreads();     // h (writes from previous phase) ready for reads
    const bf16_t* W = Wt + L * 65536;
    const float* bias = biases[L];

    f32x4 acc[4][4];
    #pragma unroll
    for (int mt = 0; mt < 4; ++mt)
      #pragma unroll
      for (int nt = 0; nt < 4; ++nt)
        #pragma unroll
        for (int e = 0; e < 4; ++e) acc[mt][nt][e] = 0.f;

    #pragma unroll
    for (int ks = 0; ks < 8; ++ks) {
      int k0 = ks * 32 + q * 8;    // this lane's 8-element k-run
      bf16x8 a[4], bb[4];
      #pragma unroll
      for (int mt = 0; mt < 4; ++mt) {
        int row = mt * 16 + r;
        a[mt] = *(const bf16x8*)&hbuf[row][swz(row, k0)];
      }
      #pragma unroll
      for (int nt = 0; nt < 4; ++nt)
        bb[nt] = *(const bf16x8*)&W[(n0 + nt * 16 + r) * 256 + k0];
      #pragma unroll
      for (int mt = 0; mt < 4; ++mt)
        #pragma unroll
        for (int nt = 0; nt < 4; ++nt)
          acc[mt][nt] = __builtin_amdgcn_mfma_f32_16x16x32_bf16(
              a[mt], bb[nt], acc[mt][nt], 0, 0, 0);
    }

    float bv[4];
    #pragma unroll
    for (int nt = 0; nt < 4; ++nt) bv[nt] = bias[n0 + nt * 16 + r];

    if (L < 2) {
      __syncthreads();   // all reads of hbuf done -> safe to overwrite
      #pragma unroll
      for (int mt = 0; mt < 4; ++mt)
        #pragma unroll
        for (int nt = 0; nt < 4; ++nt) {
          int col = n0 + nt * 16 + r;
          #pragma unroll
          for (int rg = 0; rg < 4; ++rg) {
            int row = mt * 16 + q * 4 + rg;   // D layout: row = quad*4 + reg
            hbuf[row][swz(row, col)] =
                (bf16_t)fmaxf(acc[mt][nt][rg] + bv[nt], 0.f);
          }
        }
    } else {
      // last layer: bias+relu in fp32, reduce over all 64 rows, atomic to xg
      #pragma unroll
      for (int nt = 0; nt < 4; ++nt) {
        float s = 0.f;
        #pragma unroll
        for (int mt = 0; mt < 4; ++mt)
          #pragma unroll
          for (int rg = 0; rg < 4; ++rg)
            s += fmaxf(acc[mt][nt][rg] + bv[nt], 0.f);
        s += __shfl_xor(s, 16, 64);
        s += __shfl_xor(s, 32, 64);
        if (q == 0) atomicAdd(&xg[b * 256 + n0 + nt * 16 + r], s);
      }
    }
  }
}

// ---------------- f-MLP + log_softmax (tiny, fp32) ----------------
__global__ __launch_bounds__(256) void rn_f_kernel(
    const float* __restrict__ xg,
    const float* __restrict__ f1w, const float* __restrict__ f1b,
    const float* __restrict__ f2w, const float* __restrict__ f2b,
    const float* __restrict__ f3w, const float* __restrict__ f3b,
    float* __restrict__ out)
{
  __shared__ float xs[256], t1[256], t2[256], lg[28], lse[1];
  int b = blockIdx.x, tid = threadIdx.x;
  xs[tid] = xg[b * 256 + tid];
  __syncthreads();
  float acc = f1b[tid];
  for (int k = 0; k < 256; ++k) acc += xs[k] * f1w[k * 256 + tid];
  t1[tid] = fmaxf(acc, 0.f);
  __syncthreads();
  acc = f2b[tid];
  for (int k = 0; k < 256; ++k) acc += t1[k] * f2w[k * 256 + tid];
  t2[tid] = fmaxf(acc, 0.f);
  __syncthreads();
  if (tid < 28) {
    float a2 = f3b[tid];
    for (int k = 0; k < 256; ++k) a2 += t2[k] * f3w[k * 28 + tid];
    lg[tid] = a2;
  }
  __syncthreads();
  if (tid == 0) {
    float m = lg[0];
    for (int j = 1; j < 28; ++j) m = fmaxf(m, lg[j]);
    float se = 0.f;
    for (int j = 0; j < 28; ++j) se += expf(lg[j] - m);
    lse[0] = m + logf(se);
  }
  __syncthreads();
  if (tid < 28) out[b * 28 + tid] = lg[tid] - lse[0];
}

// ---------------------------------------------------------------------------
extern "C" void kernel_launch(void* const* d_in, const int* in_sizes, int n_in,
                              void* d_out, int out_size, void* d_ws, size_t ws_size,
                              hipStream_t stream) {
  (void)in_sizes; (void)n_in; (void)out_size; (void)ws_size;
  const float* x   = (const float*)d_in[0];
  const float* qst = (const float*)d_in[1];
  const float* g1w = (const float*)d_in[2];
  const float* g1b = (const float*)d_in[3];
  const float* g2w = (const float*)d_in[4];
  const float* g2b = (const float*)d_in[5];
  const float* g3w = (const float*)d_in[6];
  const float* g3b = (const float*)d_in[7];
  const float* g4w = (const float*)d_in[8];
  const float* g4b = (const float*)d_in[9];
  const float* f1w = (const float*)d_in[10];
  const float* f1b = (const float*)d_in[11];
  const float* f2w = (const float*)d_in[12];
  const float* f2b = (const float*)d_in[13];
  const float* f3w = (const float*)d_in[14];
  const float* f3b = (const float*)d_in[15];
  float* out = (float*)d_out;

  float*  A  = (float*)d_ws;
  float*  C  = A + 4096 * 256;
  bf16_t* Wt = (bf16_t*)(C + 4096 * 256);
  float*  xg = (float*)((char*)Wt + 3 * 65536 * sizeof(bf16_t));

  rn_prep_kernel<<<256 + 768 + 64, 256, 0, stream>>>(
      x, qst, g1w, g1b, g2w, g3w, g4w, A, C, Wt, xg);
  rn_main_kernel<<<4096, 256, 0, stream>>>(A, C, Wt, g2b, g3b, g4b, xg);
  rn_f_kernel<<<64, 256, 0, stream>>>(xg, f1w, f1b, f2w, f2b, f3w, f3b, out);
}

// Round 4
// 318.422 us; speedup vs baseline: 1.1867x; 1.1867x over previous
//
#include <hip/hip_runtime.h>

typedef __bf16 bf16_t;
typedef __bf16 bf16x8 __attribute__((ext_vector_type(8)));
typedef __bf16 bf16x4 __attribute__((ext_vector_type(4)));
typedef float  f32x4  __attribute__((ext_vector_type(4)));

// ---------------------------------------------------------------------------
// Workspace layout (floats unless noted):
//   A  : [4096][256] f32   (xf @ W1[0:26])                       4 MB
//   C  : [4096][256] f32   (xf @ W1[26:52] + qst @ W1[52:180] + b1)  4 MB
//   Wt : 3 x [256][256] bf16, g2/g3/g4 weights transposed [out][in]  384 KB
//   xg : [64][256] f32     (pair-summed g output)                64 KB
// ---------------------------------------------------------------------------

// swizzled LDS column index: 16B-block XOR on row low bits -> conflict-free
// ds_read_b128 A-fragment reads with zero padding (stays at exactly 32 KB).
__device__ __forceinline__ int swz(int row, int col) {
  return (((col >> 3) ^ (row & 7)) << 3) | (col & 7);
}

// ---------------- prep: A, C, weight transpose+cast, zero xg ----------------
__global__ __launch_bounds__(256) void rn_prep_kernel(
    const float* __restrict__ x, const float* __restrict__ qst,
    const float* __restrict__ g1w, const float* __restrict__ g1b,
    const float* __restrict__ g2w, const float* __restrict__ g3w,
    const float* __restrict__ g4w,
    float* __restrict__ A, float* __restrict__ C,
    bf16_t* __restrict__ Wt, float* __restrict__ xg)
{
  int blk = blockIdx.x;
  int n   = threadIdx.x;  // 0..255
  if (blk < 256) {
    // block = (b, jg): rows jg*16 .. jg*16+15 of batch b; thread = output col n
    int b  = blk >> 2;
    int jg = (blk & 3) * 16;
    // qst part (independent of row): accQ = b1[n] + sum_q qst[b,q]*W1[52+q, n]
    float accQ = g1b[n];
    const float* qb = qst + b * 128;
    #pragma unroll 8
    for (int qi = 0; qi < 128; ++qi)
      accQ += qb[qi] * g1w[(52 + qi) * 256 + n];

    float w24 = g1w[24 * 256 + n], w25 = g1w[25 * 256 + n];
    float w50 = g1w[50 * 256 + n], w51 = g1w[51 * 256 + n];
    float accA[16], accC[16];
    #pragma unroll
    for (int t = 0; t < 16; ++t) {
      int j = jg + t;
      // faithful to (a/d - d/2)/(d/2.0) float arithmetic, d=8 (exact pow2 ops)
      float cx = ((float)j * 0.125f - 4.0f) * 0.25f;
      float cy = ((float)(j & 7) - 4.0f) * 0.25f;
      accA[t] = cx * w24 + cy * w25;
      accC[t] = accQ + cx * w50 + cy * w51;
    }
    for (int c = 0; c < 24; ++c) {
      float wa = g1w[c * 256 + n];
      float wc = g1w[(26 + c) * 256 + n];
      const float* xc = x + (b * 24 + c) * 64 + jg;
      #pragma unroll
      for (int t = 0; t < 16; ++t) {
        float xv = xc[t];   // uniform per thread -> scalar load
        accA[t] += xv * wa;
        accC[t] += xv * wc;
      }
    }
    #pragma unroll
    for (int t = 0; t < 16; ++t) {
      A[(b * 64 + jg + t) * 256 + n] = accA[t];
      C[(b * 64 + jg + t) * 256 + n] = accC[t];
    }
  } else if (blk < 256 + 768) {
    // transpose g2/g3/g4 [in][out] -> bf16 [out][in]
    int idx = (blk - 256) * 256 + n;       // 0..196607
    int mat = idx >> 16;
    int e   = idx & 65535;
    int k   = e & 255;        // input dim (fastest -> coalesced writes)
    int no  = e >> 8;         // output dim
    const float* W = (mat == 0) ? g2w : (mat == 1 ? g3w : g4w);
    Wt[mat * 65536 + no * 256 + k] = (bf16_t)W[k * 256 + no];
  } else {
    int idx = (blk - (256 + 768)) * 256 + n;  // 64 blocks -> 16384
    xg[idx] = 0.f;
  }
}

// ---------------- main fused g-MLP (layers 2..4) + pair sum ----------------
// one block per (b, i): M = 64 rows (j), N = K = 256.
// wave w owns output columns [w*64, w*64+64).
// SINGLE 32 KB h buffer; two barriers per layer (read phase / write phase).
// Occupancy history: R1 dbuf 2blk/CU=232us, R2 forced 4 waves -> 64 VGPR +
// 168MB spill=220us, R3 unconstrained -> >256 total regs, 1blk/CU=275us.
// min-waves=3 targets 168 total regs (104 arch + 64 acc): 3 blocks/CU, no
// meaningful spill expected.
__global__ __launch_bounds__(256, 3) void rn_main_kernel(
    const float* __restrict__ A, const float* __restrict__ C,
    const bf16_t* __restrict__ Wt,
    const float* __restrict__ g2b, const float* __restrict__ g3b,
    const float* __restrict__ g4b,
    float* __restrict__ xg)
{
  __shared__ bf16_t hbuf[64][256];   // exactly 32 KB, XOR-swizzled cols

  int tid  = threadIdx.x;
  int bx   = blockIdx.x;
  int b    = bx >> 6;
  int lane = tid & 63;
  int wave = tid >> 6;
  int n0   = wave * 64;

  // ---- build h1 = relu(A[b,j,:] + C[b,i,:]) into hbuf ----
  {
    const float* Crow = C + (size_t)bx * 256;        // row (b*64 + i)
    const float* Ab   = A + (size_t)b * 64 * 256;
    #pragma unroll
    for (int it = 0; it < 16; ++it) {
      int g = it * 256 + tid;
      int j = g >> 6;
      int n = (g & 63) * 4;
      const float4 a4 = *(const float4*)(Ab + j * 256 + n);
      const float4 c4 = *(const float4*)(Crow + n);
      bf16x4 v;
      v[0] = (bf16_t)fmaxf(a4.x + c4.x, 0.f);
      v[1] = (bf16_t)fmaxf(a4.y + c4.y, 0.f);
      v[2] = (bf16_t)fmaxf(a4.z + c4.z, 0.f);
      v[3] = (bf16_t)fmaxf(a4.w + c4.w, 0.f);
      *(bf16x4*)&hbuf[j][swz(j, n)] = v;
    }
  }

  const float* biases[3] = {g2b, g3b, g4b};
  int r = lane & 15;     // MFMA: A-row / B-col / D-col within 16x16 tile
  int q = lane >> 4;     // quad: k-chunk selector / D-row group

  for (int L = 0; L < 3; ++L) {
    __syncthreads();     // h (writes from previous phase) ready for reads
    const bf16_t* W = Wt + L * 65536;
    const float* bias = biases[L];

    f32x4 acc[4][4];
    #pragma unroll
    for (int mt = 0; mt < 4; ++mt)
      #pragma unroll
      for (int nt = 0; nt < 4; ++nt)
        #pragma unroll
        for (int e = 0; e < 4; ++e) acc[mt][nt][e] = 0.f;

    #pragma unroll
    for (int ks = 0; ks < 8; ++ks) {
      int k0 = ks * 32 + q * 8;    // this lane's 8-element k-run
      bf16x8 a[4], bb[4];
      #pragma unroll
      for (int mt = 0; mt < 4; ++mt) {
        int row = mt * 16 + r;
        a[mt] = *(const bf16x8*)&hbuf[row][swz(row, k0)];
      }
      #pragma unroll
      for (int nt = 0; nt < 4; ++nt)
        bb[nt] = *(const bf16x8*)&W[(n0 + nt * 16 + r) * 256 + k0];
      #pragma unroll
      for (int mt = 0; mt < 4; ++mt)
        #pragma unroll
        for (int nt = 0; nt < 4; ++nt)
          acc[mt][nt] = __builtin_amdgcn_mfma_f32_16x16x32_bf16(
              a[mt], bb[nt], acc[mt][nt], 0, 0, 0);
    }

    float bv[4];
    #pragma unroll
    for (int nt = 0; nt < 4; ++nt) bv[nt] = bias[n0 + nt * 16 + r];

    if (L < 2) {
      __syncthreads();   // all reads of hbuf done -> safe to overwrite
      #pragma unroll
      for (int mt = 0; mt < 4; ++mt)
        #pragma unroll
        for (int nt = 0; nt < 4; ++nt) {
          int col = n0 + nt * 16 + r;
          #pragma unroll
          for (int rg = 0; rg < 4; ++rg) {
            int row = mt * 16 + q * 4 + rg;   // D layout: row = quad*4 + reg
            hbuf[row][swz(row, col)] =
                (bf16_t)fmaxf(acc[mt][nt][rg] + bv[nt], 0.f);
          }
        }
    } else {
      // last layer: bias+relu in fp32, reduce over all 64 rows, atomic to xg
      #pragma unroll
      for (int nt = 0; nt < 4; ++nt) {
        float s = 0.f;
        #pragma unroll
        for (int mt = 0; mt < 4; ++mt)
          #pragma unroll
          for (int rg = 0; rg < 4; ++rg)
            s += fmaxf(acc[mt][nt][rg] + bv[nt], 0.f);
        s += __shfl_xor(s, 16, 64);
        s += __shfl_xor(s, 32, 64);
        if (q == 0) atomicAdd(&xg[b * 256 + n0 + nt * 16 + r], s);
      }
    }
  }
}

// ---------------- f-MLP + log_softmax (tiny, fp32) ----------------
__global__ __launch_bounds__(256) void rn_f_kernel(
    const float* __restrict__ xg,
    const float* __restrict__ f1w, const float* __restrict__ f1b,
    const float* __restrict__ f2w, const float* __restrict__ f2b,
    const float* __restrict__ f3w, const float* __restrict__ f3b,
    float* __restrict__ out)
{
  __shared__ float xs[256], t1[256], t2[256], lg[28], lse[1];
  int b = blockIdx.x, tid = threadIdx.x;
  xs[tid] = xg[b * 256 + tid];
  __syncthreads();
  float acc = f1b[tid];
  for (int k = 0; k < 256; ++k) acc += xs[k] * f1w[k * 256 + tid];
  t1[tid] = fmaxf(acc, 0.f);
  __syncthreads();
  acc = f2b[tid];
  for (int k = 0; k < 256; ++k) acc += t1[k] * f2w[k * 256 + tid];
  t2[tid] = fmaxf(acc, 0.f);
  __syncthreads();
  if (tid < 28) {
    float a2 = f3b[tid];
    for (int k = 0; k < 256; ++k) a2 += t2[k] * f3w[k * 28 + tid];
    lg[tid] = a2;
  }
  __syncthreads();
  if (tid == 0) {
    float m = lg[0];
    for (int j = 1; j < 28; ++j) m = fmaxf(m, lg[j]);
    float se = 0.f;
    for (int j = 0; j < 28; ++j) se += expf(lg[j] - m);
    lse[0] = m + logf(se);
  }
  __syncthreads();
  if (tid < 28) out[b * 28 + tid] = lg[tid] - lse[0];
}

// ---------------------------------------------------------------------------
extern "C" void kernel_launch(void* const* d_in, const int* in_sizes, int n_in,
                              void* d_out, int out_size, void* d_ws, size_t ws_size,
                              hipStream_t stream) {
  (void)in_sizes; (void)n_in; (void)out_size; (void)ws_size;
  const float* x   = (const float*)d_in[0];
  const float* qst = (const float*)d_in[1];
  const float* g1w = (const float*)d_in[2];
  const float* g1b = (const float*)d_in[3];
  const float* g2w = (const float*)d_in[4];
  const float* g2b = (const float*)d_in[5];
  const float* g3w = (const float*)d_in[6];
  const float* g3b = (const float*)d_in[7];
  const float* g4w = (const float*)d_in[8];
  const float* g4b = (const float*)d_in[9];
  const float* f1w = (const float*)d_in[10];
  const float* f1b = (const float*)d_in[11];
  const float* f2w = (const float*)d_in[12];
  const float* f2b = (const float*)d_in[13];
  const float* f3w = (const float*)d_in[14];
  const float* f3b = (const float*)d_in[15];
  float* out = (float*)d_out;

  float*  A  = (float*)d_ws;
  float*  C  = A + 4096 * 256;
  bf16_t* Wt = (bf16_t*)(C + 4096 * 256);
  float*  xg = (float*)((char*)Wt + 3 * 65536 * sizeof(bf16_t));

  rn_prep_kernel<<<256 + 768 + 64, 256, 0, stream>>>(
      x, qst, g1w, g1b, g2w, g3w, g4w, A, C, Wt, xg);
  rn_main_kernel<<<4096, 256, 0, stream>>>(A, C, Wt, g2b, g3b, g4b, xg);
  rn_f_kernel<<<64, 256, 0, stream>>>(xg, f1w, f1b, f2w, f2b, f3w, f3b, out);
}

// Round 5
// 254.091 us; speedup vs baseline: 1.4872x; 1.2532x over previous
//
#include <hip/hip_runtime.h>

typedef __bf16 bf16_t;
typedef __bf16 bf16x8 __attribute__((ext_vector_type(8)));
typedef __bf16 bf16x4 __attribute__((ext_vector_type(4)));
typedef float  f32x4  __attribute__((ext_vector_type(4)));

// ---------------------------------------------------------------------------
// Workspace layout (floats unless noted):
//   A  : [4096][256] f32   (xf @ W1[0:26])                       4 MB
//   C  : [4096][256] f32   (xf @ W1[26:52] + qst @ W1[52:180] + b1)  4 MB
//   Wt : 3 x [256][256] bf16, g2/g3/g4 weights transposed [out][in]  384 KB
//   xg : [64][256] f32     (pair-summed g output)                64 KB
// ---------------------------------------------------------------------------

// swizzled LDS column index: 16B-block XOR on row low bits.
__device__ __forceinline__ int swz(int row, int col) {
  return (((col >> 3) ^ (row & 7)) << 3) | (col & 7);
}

// ---------------- prep: A, C, weight transpose+cast, zero xg ----------------
__global__ __launch_bounds__(256) void rn_prep_kernel(
    const float* __restrict__ x, const float* __restrict__ qst,
    const float* __restrict__ g1w, const float* __restrict__ g1b,
    const float* __restrict__ g2w, const float* __restrict__ g3w,
    const float* __restrict__ g4w,
    float* __restrict__ A, float* __restrict__ C,
    bf16_t* __restrict__ Wt, float* __restrict__ xg)
{
  __shared__ float T[64][65];   // transpose tile (only used by that branch)
  int blk = blockIdx.x;
  int n   = threadIdx.x;  // 0..255
  if (blk < 256) {
    // block = (b, jg): rows jg*16 .. jg*16+15 of batch b; thread = output col n
    int b  = blk >> 2;
    int jg = (blk & 3) * 16;
    float accQ = g1b[n];
    const float* qb = qst + b * 128;
    #pragma unroll 8
    for (int qi = 0; qi < 128; ++qi)
      accQ += qb[qi] * g1w[(52 + qi) * 256 + n];

    float w24 = g1w[24 * 256 + n], w25 = g1w[25 * 256 + n];
    float w50 = g1w[50 * 256 + n], w51 = g1w[51 * 256 + n];
    float accA[16], accC[16];
    #pragma unroll
    for (int t = 0; t < 16; ++t) {
      int j = jg + t;
      // faithful to (a/d - d/2)/(d/2.0) float arithmetic, d=8 (exact pow2 ops)
      float cx = ((float)j * 0.125f - 4.0f) * 0.25f;
      float cy = ((float)(j & 7) - 4.0f) * 0.25f;
      accA[t] = cx * w24 + cy * w25;
      accC[t] = accQ + cx * w50 + cy * w51;
    }
    for (int c = 0; c < 24; ++c) {
      float wa = g1w[c * 256 + n];
      float wc = g1w[(26 + c) * 256 + n];
      const float* xc = x + (b * 24 + c) * 64 + jg;
      #pragma unroll
      for (int t = 0; t < 16; ++t) {
        float xv = xc[t];   // uniform per thread -> scalar load
        accA[t] += xv * wa;
        accC[t] += xv * wc;
      }
    }
    #pragma unroll
    for (int t = 0; t < 16; ++t) {
      A[(b * 64 + jg + t) * 256 + n] = accA[t];
      C[(b * 64 + jg + t) * 256 + n] = accC[t];
    }
  } else if (blk < 256 + 48) {
    // LDS-tiled transpose: g2/g3/g4 [in(k)][out(no)] f32 -> bf16 [no][k]
    int t   = blk - 256;
    int mat = t >> 4;                 // 0..2
    int tl  = t & 15;                 // 4x4 tiles of 64x64
    int kt  = (tl & 3) * 64;
    int nt_ = (tl >> 2) * 64;
    const float* W = (mat == 0) ? g2w : (mat == 1 ? g3w : g4w);
    int lane = n & 63, w = n >> 6;
    #pragma unroll
    for (int it = 0; it < 16; ++it) {
      int kl = w * 16 + it;
      T[kl][lane] = W[(kt + kl) * 256 + nt_ + lane];   // coalesced 256B/wave
    }
    __syncthreads();
    #pragma unroll
    for (int it = 0; it < 16; ++it) {
      int nl = w * 16 + it;
      Wt[mat * 65536 + (nt_ + nl) * 256 + kt + lane] = (bf16_t)T[lane][nl];
    }
  } else {
    int idx = (blk - (256 + 48)) * 256 + n;  // 64 blocks -> 16384
    xg[idx] = 0.f;
  }
}

// ---------------- main fused g-MLP (layers 2..4) + pair sum ----------------
// one block per (b, i-pair): M = 128 rows (2 i-values x 64 j), N = K = 256.
// Operand-swapped MFMA: A-operand = W (n-index -> D rows), B-operand = h
// (m-index -> D cols). D: col=lane&15=m-within, row=quad*4+rg=n-within ->
// epilogue writes are row-contiguous bf16x4 (b64), not scalar.
// Single 64 KB h buffer, two barriers/layer. launch_bounds(256,2): 256-reg
// budget (acc=128 + frags ~48 + addr fits), 2 blocks/CU.
__global__ __launch_bounds__(256, 2) void rn_main_kernel(
    const float* __restrict__ A, const float* __restrict__ C,
    const bf16_t* __restrict__ Wt,
    const float* __restrict__ g2b, const float* __restrict__ g3b,
    const float* __restrict__ g4b,
    float* __restrict__ xg)
{
  __shared__ bf16_t hbuf[128][256];   // exactly 64 KB, XOR-swizzled cols

  int tid  = threadIdx.x;
  int bx   = blockIdx.x;
  int b    = bx >> 5;          // batch
  int ip   = bx & 31;          // i-pair: i = 2*ip, 2*ip+1
  int lane = tid & 63;
  int wave = tid >> 6;
  int n0   = wave * 64;

  // ---- build h1 rows: row = ii*64 + j = relu(A[b,j,:] + C[b,2ip+ii,:]) ----
  {
    const float* Ab = A + (size_t)b * 64 * 256;
    const float* Cr = C + ((size_t)b * 64 + ip * 2) * 256;
    #pragma unroll
    for (int it = 0; it < 16; ++it) {
      int g = it * 256 + tid;
      int j = g >> 6;
      int n = (g & 63) * 4;
      const float4 a4 = *(const float4*)(Ab + j * 256 + n);
      const float4 c0 = *(const float4*)(Cr + n);
      const float4 c1 = *(const float4*)(Cr + 256 + n);
      bf16x4 v0, v1;
      v0[0] = (bf16_t)fmaxf(a4.x + c0.x, 0.f);
      v0[1] = (bf16_t)fmaxf(a4.y + c0.y, 0.f);
      v0[2] = (bf16_t)fmaxf(a4.z + c0.z, 0.f);
      v0[3] = (bf16_t)fmaxf(a4.w + c0.w, 0.f);
      v1[0] = (bf16_t)fmaxf(a4.x + c1.x, 0.f);
      v1[1] = (bf16_t)fmaxf(a4.y + c1.y, 0.f);
      v1[2] = (bf16_t)fmaxf(a4.z + c1.z, 0.f);
      v1[3] = (bf16_t)fmaxf(a4.w + c1.w, 0.f);
      *(bf16x4*)&hbuf[j][swz(j, n)] = v0;
      *(bf16x4*)&hbuf[64 + j][swz(64 + j, n)] = v1;
    }
  }

  const float* biases[3] = {g2b, g3b, g4b};
  int r = lane & 15;     // 16-dim index within MFMA tile
  int q = lane >> 4;     // quad: k-chunk selector / D-row group

  for (int L = 0; L < 3; ++L) {
    __syncthreads();     // h ready for reads
    const bf16_t* W = Wt + L * 65536;
    const float* bias = biases[L];

    f32x4 acc[4][8];     // [nt][mt]
    #pragma unroll
    for (int nt = 0; nt < 4; ++nt)
      #pragma unroll
      for (int mt = 0; mt < 8; ++mt)
        #pragma unroll
        for (int e = 0; e < 4; ++e) acc[nt][mt][e] = 0.f;

    #pragma unroll
    for (int ks = 0; ks < 8; ++ks) {
      int k0 = ks * 32 + q * 8;    // this lane's 8-element k-run
      bf16x8 wf[4], hf[8];
      #pragma unroll
      for (int nt = 0; nt < 4; ++nt)
        wf[nt] = *(const bf16x8*)&W[(n0 + nt * 16 + r) * 256 + k0];
      #pragma unroll
      for (int mt = 0; mt < 8; ++mt) {
        int row = mt * 16 + r;
        hf[mt] = *(const bf16x8*)&hbuf[row][swz(row, k0)];
      }
      #pragma unroll
      for (int nt = 0; nt < 4; ++nt)
        #pragma unroll
        for (int mt = 0; mt < 8; ++mt)
          acc[nt][mt] = __builtin_amdgcn_mfma_f32_16x16x32_bf16(
              wf[nt], hf[mt], acc[nt][mt], 0, 0, 0);
    }

    float4 bv[4];        // biases for n = n0 + nt*16 + q*4 + rg
    #pragma unroll
    for (int nt = 0; nt < 4; ++nt)
      bv[nt] = *(const float4*)&bias[n0 + nt * 16 + q * 4];

    if (L < 2) {
      __syncthreads();   // all reads of hbuf done -> safe to overwrite
      #pragma unroll
      for (int nt = 0; nt < 4; ++nt) {
        int col = n0 + nt * 16 + q * 4;
        #pragma unroll
        for (int mt = 0; mt < 8; ++mt) {
          int row = mt * 16 + r;
          bf16x4 v;
          v[0] = (bf16_t)fmaxf(acc[nt][mt][0] + bv[nt].x, 0.f);
          v[1] = (bf16_t)fmaxf(acc[nt][mt][1] + bv[nt].y, 0.f);
          v[2] = (bf16_t)fmaxf(acc[nt][mt][2] + bv[nt].z, 0.f);
          v[3] = (bf16_t)fmaxf(acc[nt][mt][3] + bv[nt].w, 0.f);
          *(bf16x4*)&hbuf[row][swz(row, col)] = v;
        }
      }
    } else {
      // last layer: bias+relu fp32, sum over all 128 m-rows, atomic to xg.
      // m = mt*16 + r: sum over mt in-register, then over the 16 r-lanes.
      #pragma unroll
      for (int nt = 0; nt < 4; ++nt) {
        float p0 = 0.f, p1 = 0.f, p2 = 0.f, p3 = 0.f;
        #pragma unroll
        for (int mt = 0; mt < 8; ++mt) {
          p0 += fmaxf(acc[nt][mt][0] + bv[nt].x, 0.f);
          p1 += fmaxf(acc[nt][mt][1] + bv[nt].y, 0.f);
          p2 += fmaxf(acc[nt][mt][2] + bv[nt].z, 0.f);
          p3 += fmaxf(acc[nt][mt][3] + bv[nt].w, 0.f);
        }
        #pragma unroll
        for (int d = 1; d < 16; d <<= 1) {
          p0 += __shfl_xor(p0, d, 64);
          p1 += __shfl_xor(p1, d, 64);
          p2 += __shfl_xor(p2, d, 64);
          p3 += __shfl_xor(p3, d, 64);
        }
        if (r == 0) {
          int n = b * 256 + n0 + nt * 16 + q * 4;
          atomicAdd(&xg[n + 0], p0);
          atomicAdd(&xg[n + 1], p1);
          atomicAdd(&xg[n + 2], p2);
          atomicAdd(&xg[n + 3], p3);
        }
      }
    }
  }
}

// ---------------- f-MLP + log_softmax (tiny, fp32) ----------------
__global__ __launch_bounds__(256) void rn_f_kernel(
    const float* __restrict__ xg,
    const float* __restrict__ f1w, const float* __restrict__ f1b,
    const float* __restrict__ f2w, const float* __restrict__ f2b,
    const float* __restrict__ f3w, const float* __restrict__ f3b,
    float* __restrict__ out)
{
  __shared__ float xs[256], t1[256], t2[256], lg[28], lse[1];
  int b = blockIdx.x, tid = threadIdx.x;
  xs[tid] = xg[b * 256 + tid];
  __syncthreads();
  float acc = f1b[tid];
  for (int k = 0; k < 256; ++k) acc += xs[k] * f1w[k * 256 + tid];
  t1[tid] = fmaxf(acc, 0.f);
  __syncthreads();
  acc = f2b[tid];
  for (int k = 0; k < 256; ++k) acc += t1[k] * f2w[k * 256 + tid];
  t2[tid] = fmaxf(acc, 0.f);
  __syncthreads();
  if (tid < 28) {
    float a2 = f3b[tid];
    for (int k = 0; k < 256; ++k) a2 += t2[k] * f3w[k * 28 + tid];
    lg[tid] = a2;
  }
  __syncthreads();
  if (tid == 0) {
    float m = lg[0];
    for (int j = 1; j < 28; ++j) m = fmaxf(m, lg[j]);
    float se = 0.f;
    for (int j = 0; j < 28; ++j) se += expf(lg[j] - m);
    lse[0] = m + logf(se);
  }
  __syncthreads();
  if (tid < 28) out[b * 28 + tid] = lg[tid] - lse[0];
}

// ---------------------------------------------------------------------------
extern "C" void kernel_launch(void* const* d_in, const int* in_sizes, int n_in,
                              void* d_out, int out_size, void* d_ws, size_t ws_size,
                              hipStream_t stream) {
  (void)in_sizes; (void)n_in; (void)out_size; (void)ws_size;
  const float* x   = (const float*)d_in[0];
  const float* qst = (const float*)d_in[1];
  const float* g1w = (const float*)d_in[2];
  const float* g1b = (const float*)d_in[3];
  const float* g2w = (const float*)d_in[4];
  const float* g2b = (const float*)d_in[5];
  const float* g3w = (const float*)d_in[6];
  const float* g3b = (const float*)d_in[7];
  const float* g4w = (const float*)d_in[8];
  const float* g4b = (const float*)d_in[9];
  const float* f1w = (const float*)d_in[10];
  const float* f1b = (const float*)d_in[11];
  const float* f2w = (const float*)d_in[12];
  const float* f2b = (const float*)d_in[13];
  const float* f3w = (const float*)d_in[14];
  const float* f3b = (const float*)d_in[15];
  float* out = (float*)d_out;

  float*  A  = (float*)d_ws;
  float*  C  = A + 4096 * 256;
  bf16_t* Wt = (bf16_t*)(C + 4096 * 256);
  float*  xg = (float*)((char*)Wt + 3 * 65536 * sizeof(bf16_t));

  rn_prep_kernel<<<256 + 48 + 64, 256, 0, stream>>>(
      x, qst, g1w, g1b, g2w, g3w, g4w, A, C, Wt, xg);
  rn_main_kernel<<<2048, 256, 0, stream>>>(A, C, Wt, g2b, g3b, g4b, xg);
  rn_f_kernel<<<64, 256, 0, stream>>>(xg, f1w, f1b, f2w, f2b, f3w, f3b, out);
}